// Round 6
// baseline (820.321 us; speedup 1.0000x reference)
//
#include <hip/hip_runtime.h>
#include <stdint.h>

#define NTOT   12288
#define NW     192           // NTOT/64 suppression-mask words
#define NCH    6
#define RECB   25600         // bytes per block record (25 x 1KB chunks)
#define RECW   (RECB/4)      // u32 per record
#define NCHK   25            // global_load_lds 1KB chunks per record
#define EMAX   1536          // CSR entry capacity per block
#define CONF_THR 0.01f
#define NMS_THR  0.45f

typedef unsigned long long u64;
typedef uint32_t u32;

__device__ __forceinline__ float sigmf(float x){ return 1.0f/(1.0f+expf(-x)); }

// exact reference IoU-suppression test
__device__ __forceinline__ bool sup_pair(float ax1,float ay1,float ax2,float ay2,float aar,
                                         float bx1,float by1,float bx2,float by2,float bar){
  float tlx=fmaxf(ax1,bx1), tly=fmaxf(ay1,by1);
  float brx=fminf(ax2,bx2), bry=fminf(ay2,by2);
  float inter=(brx-tlx)*(bry-tly);
  if(!(tlx<brx && tly<bry)) inter=0.0f;
  float iou = inter/((aar+bar)-inter);
  return iou >= NMS_THR;
}

__device__ __forceinline__ u64 rfl64(u64 v){
  u32 lo = (u32)__builtin_amdgcn_readfirstlane((int)(u32)(v & 0xffffffffull));
  u32 hi = (u32)__builtin_amdgcn_readfirstlane((int)(u32)(v>>32));
  return (((u64)hi)<<32) | (u64)lo;
}
__device__ __forceinline__ u64 rdlane64(u64 v, int src){
  u32 lo = (u32)__builtin_amdgcn_readlane((int)(u32)(v & 0xffffffffull), src);
  u32 hi = (u32)__builtin_amdgcn_readlane((int)(u32)(v>>32), src);
  return (((u64)hi)<<32) | (u64)lo;
}
__device__ __forceinline__ void dma16(const void* g, void* l){
  __builtin_amdgcn_global_load_lds((const __attribute__((address_space(1))) void*)g,
                                   (__attribute__((address_space(3))) void*)l, 16, 0, 0);
}

// ---------------- decode ----------------
__global__ void k_decode(const float* __restrict__ feat, const float* __restrict__ anchors,
                         float4* __restrict__ obox, float* __restrict__ oobj,
                         float* __restrict__ ocls, float* __restrict__ oscore,
                         u32* __restrict__ okey, int* __restrict__ rank){
  int n = blockIdx.x*256 + threadIdx.x;
  int a = n >> 12;
  int cell = n & 4095;
  int gy = cell >> 6, gx = cell & 63;
  const float* f = feat + a*NCH*4096 + cell;
  float v0=f[0], v1=f[4096], v2=f[8192], v3=f[12288], v4=f[16384], v5=f[20480];
  float aw = anchors[2*a]   * 0.125f;
  float ah = anchors[2*a+1] * 0.125f;
  float px = (sigmf(v0) + (float)gx) * 8.0f;
  float py = (sigmf(v1) + (float)gy) * 8.0f;
  float pw = (expf(v2)*aw) * 8.0f;
  float ph = (expf(v3)*ah) * 8.0f;
  float obj = sigmf(v4), cls = sigmf(v5);
  float4 b;
  b.x = px - pw*0.5f; b.y = py - ph*0.5f;
  b.z = px + pw*0.5f; b.w = py + ph*0.5f;
  float sc = obj*cls;
  obox[n]=b; oobj[n]=obj; ocls[n]=cls; oscore[n]=sc;
  u32 u = __float_as_uint(sc);
  u32 asc = (u & 0x80000000u) ? ~u : (u | 0x80000000u);
  okey[n] = ~asc;            // descending: higher score -> smaller key
  rank[n] = 0;
}

// ---------------- partial rank over a 1024-key slice ----------------
__global__ __launch_bounds__(256) void k_rank_part(const u32* __restrict__ okey,
                                                   int* __restrict__ rank){
  __shared__ u32 tile[1024];
  int n = blockIdx.x*256 + threadIdx.x;
  int t0 = blockIdx.y * 1024;
  u32 my = okey[n];
  for(int k=threadIdx.x;k<1024;k+=256) tile[k]=okey[t0+k];
  __syncthreads();
  int r0=0,r1=0,r2=0,r3=0;
  #pragma unroll 4
  for(int k=0;k<1024;k+=4){
    uint4 kj = *reinterpret_cast<const uint4*>(&tile[k]);
    int j = t0+k;
    r0 += (int)((kj.x<my)||(kj.x==my && (j  )<n));
    r1 += (int)((kj.y<my)||(kj.y==my && (j+1)<n));
    r2 += (int)((kj.z<my)||(kj.z==my && (j+2)<n));
    r3 += (int)((kj.w<my)||(kj.w==my && (j+3)<n));
  }
  atomicAdd(&rank[n], r0+r1+r2+r3);
}

// ---------------- scatter into sorted arrays ----------------
__global__ void k_scatter(const int* __restrict__ rank,
                          const float4* __restrict__ obox,const float* __restrict__ oobj,
                          const float* __restrict__ ocls,const float* __restrict__ oscore,
                          float4* __restrict__ sbox,float* __restrict__ sarea,
                          float* __restrict__ sobj,float* __restrict__ scls,
                          u32* __restrict__ svalid,int* __restrict__ order){
  int n = blockIdx.x*256 + threadIdx.x;
  int r = rank[n];
  float4 b = obox[n];
  sbox[r]=b;
  sarea[r]=(b.z-b.x)*(b.w-b.y);
  sobj[r]=oobj[n]; scls[r]=ocls[n];
  svalid[r] = (oscore[n] >= CONF_THR) ? 1u : 0u;
  order[r]=n;
}

// ---------------- within-word ROW masks (into records) + valid words ----------------
__global__ __launch_bounds__(256) void k_cmv(const float4* __restrict__ sbox,
                       const float* __restrict__ sarea,const u32* __restrict__ svalid,
                       char* __restrict__ recs,u64* __restrict__ validw){
  __shared__ float4 bb[256];
  __shared__ float  aa[256];
  int j = blockIdx.x*256 + threadIdx.x;
  int lane = threadIdx.x & 63;
  float4 b = sbox[j];
  float ar = sarea[j];
  bb[threadIdx.x]=b; aa[threadIdx.x]=ar;
  __syncthreads();
  int base = threadIdx.x & ~63;
  u64 myrow = 0;
  for(int t=0;t<64;t++){
    float4 a = bb[base+t]; float aar = aa[base+t];
    bool s = (lane>t) && sup_pair(a.x,a.y,a.z,a.w,aar, b.x,b.y,b.z,b.w,ar);
    u64 rw = __ballot(s);
    if(lane==t) myrow = rw;                 // row t: which j>t it suppresses (within word)
  }
  int w = j>>6;
  ((u64*)(recs + (size_t)w*RECB))[lane] = myrow;   // record bytes [0..511]
  u64 vb = __ballot(svalid[j]!=0u);
  if(lane==0) validw[w]=vb;
}

// ---------------- dense COLUMNS: colD[j][v] = suppressors of j in word v (v < j's word) ----------------
__global__ __launch_bounds__(256) void k_cols(const float4* __restrict__ sbox,
                       const float* __restrict__ sarea,u64* __restrict__ colD){
  int j   = (blockIdx.x*256 + threadIdx.x) >> 6;   // box index = wave id
  int lane = threadIdx.x & 63;
  int B = j >> 6;
  float4 bj = sbox[j];
  float aj = sarea[j];
  u64 r0=0,r1=0,r2=0;
  for(int v=0; v<B; ++v){
    int i = (v<<6) | lane;
    float4 a = sbox[i];
    bool s = sup_pair(a.x,a.y,a.z,a.w,sarea[i], bj.x,bj.y,bj.z,bj.w,aj);
    u64 word = __ballot(s);
    if(lane == (v&63)){
      int sl = v>>6;
      if(sl==0) r0=word; else if(sl==1) r1=word; else r2=word;
    }
  }
  u64* cp = colD + (size_t)j*NW;
  cp[lane]=r0; cp[64+lane]=r1; cp[128+lane]=r2;    // words v>=B stay 0 (never set)
}

// ---------------- CSR build: per block, offsets + (word,bits) entries ----------------
__global__ __launch_bounds__(64) void k_csr(const u64* __restrict__ colD,
                                            char* __restrict__ recs){
  int B = blockIdx.x;
  int lane = threadIdx.x;
  int jg = B*64 + lane;
  const u64* cp = colD + (size_t)jg*NW;
  u32 c = 0;
  for(int v=0; v<B; ++v) c += (cp[v]!=0ull) ? 1u : 0u;
  u32 inc = c;
  for(int d=1; d<64; d<<=1){ u32 x = __shfl_up(inc, d); if(lane>=d) inc += x; }
  u32 off = inc - c;
  u32 total = (u32)__shfl((int)inc, 63);
  char* R = recs + (size_t)B*RECB;
  *(u32*)(R + 516 + lane*4) = off;
  if(lane==0) *(u32*)(R + 512) = total;
  if(total <= EMAX){
    uint4* ent = (uint4*)(R + 1024);
    u32 p = off;
    for(int v=0; v<B; ++v){
      u64 bits = cp[v];
      if(bits) ent[p++] = make_uint4((u32)v, (u32)bits, (u32)(bits>>32), 0u);
    }
  }
}

// ---------------- single-wave greedy scan: pull-model column gather, readlane greedy ----------------
__global__ __launch_bounds__(64) void k_scan5(const char* __restrict__ recs,
                       const u64* __restrict__ validw_g,
                       const u64* __restrict__ colD,
                       u64* __restrict__ keepw_g){
  __shared__ __align__(16) u32 buf[3][RECW];   // 3 x 25.6KB record buffers
  __shared__ u64 keepL[NW];
  __shared__ u64 valL[NW];
  int lane = threadIdx.x;

  #pragma unroll
  for(int t=0;t<3;t++){ keepL[t*64+lane]=0ull; valL[t*64+lane]=validw_g[t*64+lane]; }

  // prologue: stage blocks 0,1,2
  for(int b=0;b<3;b++){
    const char* s = recs + (size_t)b*RECB + (size_t)lane*16;
    #pragma unroll
    for(int c=0;c<NCHK;c++) dma16(s + c*1024, &buf[b][c*256]);
  }
  asm volatile("s_waitcnt vmcnt(50)" ::: "memory");   // block 0 landed
  __builtin_amdgcn_sched_barrier(0);
  u64 rowl = (((u64)buf[0][lane*2+1])<<32) | (u64)buf[0][lane*2];
  asm volatile("s_waitcnt lgkmcnt(0)" ::: "memory");  // rowl read retired before DMA reuse
  __builtin_amdgcn_sched_barrier(0);

  u64 suppP=0, patch=0, kw_prev=0;

  for(int w=0; w<NW; ++w){
    // (a) block w+1 landed (leave w+2's 25 in flight); prior ds ops retired
    asm volatile("s_waitcnt vmcnt(25) lgkmcnt(0)" ::: "memory");
    __builtin_amdgcn_sched_barrier(0);
    // (b) stage block w+3 into buf[w%3] (its reads retired last iteration)
    {
      int nb = (w+3 < NW) ? (w+3) : (NW-1);
      const char* s = recs + (size_t)nb*RECB + (size_t)lane*16;
      u32* d = &buf[w%3][0];
      #pragma unroll
      for(int c=0;c<NCHK;c++) dma16(s + c*1024, d + c*256);
    }
    __builtin_amdgcn_sched_barrier(0);
    // (c) gather for word w+1 from buf[(w+1)%3]
    u64 rowl_n=0, suppP_n=0, patch_n=0;
    if(w+1<NW){
      const u32* B = &buf[(w+1)%3][0];
      rowl_n = (((u64)B[lane*2+1])<<32) | (u64)B[lane*2];
      u32 total = B[128];
      if(total <= EMAX){
        u32 off = B[129+lane];
        u32 nxt = (lane<63) ? B[130+lane] : total;
        u32 cnt = nxt - off;
        for(u32 e=0; e<cnt; e+=4){
          u32 i0 = 256 + (off+e)*4;
          u32 x0=B[i0], y0=B[i0+1], z0=B[i0+2];
          u32 x1=0,y1=0,z1=0, x2=0,y2=0,z2=0, x3=0,y3=0,z3=0;
          if(e+1<cnt){ x1=B[i0+4];  y1=B[i0+5];  z1=B[i0+6];  }
          if(e+2<cnt){ x2=B[i0+8];  y2=B[i0+9];  z2=B[i0+10]; }
          if(e+3<cnt){ x3=B[i0+12]; y3=B[i0+13]; z3=B[i0+14]; }
          u64 b0=(((u64)z0)<<32)|y0, b1=(((u64)z1)<<32)|y1;
          u64 b2=(((u64)z2)<<32)|y2, b3=(((u64)z3)<<32)|y3;
          u64 k0=keepL[x0], k1=keepL[x1], k2=keepL[x2], k3=keepL[x3];
          bool w0_=(x0==(u32)w), w1_=(x1==(u32)w), w2_=(x2==(u32)w), w3_=(x3==(u32)w);
          suppP_n |= b0 & (w0_?0ull:k0);  patch_n |= w0_?b0:0ull;
          suppP_n |= b1 & (w1_?0ull:k1);  patch_n |= w1_?b1:0ull;
          suppP_n |= b2 & (w2_?0ull:k2);  patch_n |= w2_?b2:0ull;
          suppP_n |= b3 & (w3_?0ull:k3);  patch_n |= w3_?b3:0ull;
        }
      } else {
        // rare: dense column walk for overflow block
        int jg = (w+1)*64 + lane;
        const u64* cp = colD + (size_t)jg*NW;
        for(int v=0; v<w; ++v) suppP_n |= cp[v] & keepL[v];
        patch_n = cp[w];
      }
    }
    // (d) finalize decision inputs for word w
    u64 supp = suppP | (patch & kw_prev);
    u64 sball = __ballot(supp != 0ull);
    u64 cand = rfl64(valL[w]) & ~sball;
    // (e) greedy: all-SALU + readlane row broadcast
    u64 keep64 = 0;
    while(cand){
      unsigned t = (unsigned)__builtin_ctzll(cand);
      keep64 |= (1ull<<t);
      cand &= ~(1ull<<t);
      u64 rt = rdlane64(rowl, (int)t);
      cand &= ~rt;
    }
    if(lane==0) keepL[w] = keep64;
    kw_prev = keep64;
    rowl = rowl_n; suppP = suppP_n; patch = patch_n;
  }
  #pragma unroll
  for(int t=0;t<3;t++) keepw_g[t*64+lane] = keepL[t*64+lane];
}

// ---------------- final output ----------------
__global__ void k_final(const int* __restrict__ order,const u64* __restrict__ keepw,
                        const float4* __restrict__ sbox,const float* __restrict__ sobj,
                        const float* __restrict__ scls,float* __restrict__ out){
  int i = blockIdx.x*256 + threadIdx.x;
  int n = order[i];
  u64 kw = keepw[i>>6];
  float kf = ((kw>>(unsigned)(i&63))&1ull) ? 1.0f : 0.0f;
  float4 b = sbox[i];
  float* det = out + (size_t)n*6;
  det[0]=b.x*kf; det[1]=b.y*kf; det[2]=b.z*kf; det[3]=b.w*kf;
  det[4]=sobj[i]*kf; det[5]=scls[i]*kf;
  out[NTOT*6 + n] = kf;
}

extern "C" void kernel_launch(void* const* d_in,const int* in_sizes,int n_in,
                              void* d_out,int out_size,void* d_ws,size_t ws_size,
                              hipStream_t stream){
  const float* feat=(const float*)d_in[0];
  const float* anchors=(const float*)d_in[1];
  float* out=(float*)d_out;

  char* w=(char*)d_ws;
  auto alloc=[&](size_t bytes)->char*{ char* p=w; w += (bytes+255)&~255ull; return p; };
  float4 *obox =(float4*)alloc(NTOT*16);
  float  *oobj =(float*) alloc(NTOT*4);
  float  *ocls =(float*) alloc(NTOT*4);
  float  *oscore=(float*)alloc(NTOT*4);
  u32    *okey =(u32*)   alloc(NTOT*4);
  int    *rank =(int*)   alloc(NTOT*4);
  float4 *sbox =(float4*)alloc(NTOT*16);
  float  *sarea=(float*) alloc(NTOT*4);
  float  *sobj =(float*) alloc(NTOT*4);
  float  *scls =(float*) alloc(NTOT*4);
  u32    *svalid=(u32*)  alloc(NTOT*4);
  int    *order=(int*)   alloc(NTOT*4);
  u64    *validw =(u64*) alloc(NW*8);
  u64    *keepw  =(u64*) alloc(NW*8);
  u64    *colD   =(u64*) alloc((size_t)NTOT*NW*8);   // 18.9 MB dense columns
  char   *recs   =(char*)alloc((size_t)NW*RECB);     // 4.9 MB block records

  hipLaunchKernelGGL(k_decode, dim3(NTOT/256),dim3(256),0,stream,
                     feat,anchors,obox,oobj,ocls,oscore,okey,rank);
  hipLaunchKernelGGL(k_rank_part, dim3(NTOT/256,12),dim3(256),0,stream, okey,rank);
  hipLaunchKernelGGL(k_scatter, dim3(NTOT/256),dim3(256),0,stream,
                     rank,obox,oobj,ocls,oscore,sbox,sarea,sobj,scls,svalid,order);
  hipLaunchKernelGGL(k_cmv, dim3(NTOT/256),dim3(256),0,stream,
                     sbox,sarea,svalid,recs,validw);
  hipLaunchKernelGGL(k_cols, dim3(NTOT/4),dim3(256),0,stream, sbox,sarea,colD);
  hipLaunchKernelGGL(k_csr, dim3(NW),dim3(64),0,stream, colD,recs);
  hipLaunchKernelGGL(k_scan5, dim3(1),dim3(64),0,stream, recs,validw,colD,keepw);
  hipLaunchKernelGGL(k_final, dim3(NTOT/256),dim3(256),0,stream,
                     order,keepw,sbox,sobj,scls,out);
}